// Round 1
// baseline (97.338 us; speedup 1.0000x reference)
//
#include <hip/hip_runtime.h>
#include <hip/hip_bf16.h>
#include <math.h>

#define HID 2048
#define MAXLEN 128
#define VOCAB 32000

// ---------- reduction helper: 256-thread block (4 waves) ----------
__device__ __forceinline__ float block_reduce_sum256(float v) {
    // wave-level butterfly (64 lanes)
    for (int off = 32; off > 0; off >>= 1) v += __shfl_down(v, off, 64);
    __shared__ float s[4];
    int lane = threadIdx.x & 63, w = threadIdx.x >> 6;
    if (lane == 0) s[w] = v;
    __syncthreads();
    float r = 0.f;
    if (threadIdx.x == 0) r = s[0] + s[1] + s[2] + s[3];
    return r;
}

// ---------- gather embedding row: x = emb[tok] ----------
__global__ void gather_row_kernel(const float* __restrict__ emb,
                                  const int* __restrict__ tok,
                                  float* __restrict__ x) {
    int i = blockIdx.x * blockDim.x + threadIdx.x;
    if (i < HID) x[i] = emb[(size_t)tok[0] * HID + i];
}

// ---------- dual matvec + bias + activation: out[r] = act(W1[r]·x1 + W2[r]·x2 + b1[r] + b2[r]) ----------
// act: 0 = none, 1 = tanh, 2 = relu
__global__ void dual_matvec_kernel(const float* __restrict__ W1, const float* __restrict__ x1,
                                   const float* __restrict__ W2, const float* __restrict__ x2,
                                   const float* __restrict__ b1, const float* __restrict__ b2,
                                   float* __restrict__ out, int act) {
    int r = blockIdx.x;
    const float4* w1 = (const float4*)(W1 + (size_t)r * HID);
    const float4* w2 = (const float4*)(W2 + (size_t)r * HID);
    const float4* v1 = (const float4*)x1;
    const float4* v2 = (const float4*)x2;
    const int K4 = HID / 4;  // 512
    float p = 0.f;
    for (int i = threadIdx.x; i < K4; i += blockDim.x) {
        float4 a = w1[i], b = v1[i];
        p += a.x * b.x + a.y * b.y + a.z * b.z + a.w * b.w;
        float4 c = w2[i], d = v2[i];
        p += c.x * d.x + c.y * d.y + c.z * d.z + c.w * d.w;
    }
    float s = block_reduce_sum256(p);
    if (threadIdx.x == 0) {
        s += b1[r] + b2[r];
        if (act == 1) s = tanhf(s);
        else if (act == 2) s = fmaxf(s, 0.f);
        out[r] = s;
    }
}

// ---------- concat matvec: out[r] = act(W[r, 0:H]·xa + W[r, H:2H]·xb + bias[r]) ----------
__global__ void concat_matvec_kernel(const float* __restrict__ W,
                                     const float* __restrict__ xa, const float* __restrict__ xb,
                                     const float* __restrict__ bias,
                                     float* __restrict__ out, int act) {
    int r = blockIdx.x;
    const float4* w = (const float4*)(W + (size_t)r * (2 * HID));
    const float4* va = (const float4*)xa;
    const float4* vb = (const float4*)xb;
    const int K4 = HID / 4;  // 512 per half
    float p = 0.f;
    for (int i = threadIdx.x; i < K4; i += blockDim.x) {
        float4 a = w[i], b = va[i];
        p += a.x * b.x + a.y * b.y + a.z * b.z + a.w * b.w;
        float4 c = w[i + K4], d = vb[i];
        p += c.x * d.x + c.y * d.y + c.z * d.z + c.w * d.w;
    }
    float s = block_reduce_sum256(p);
    if (threadIdx.x == 0) {
        s += bias[r];
        if (act == 1) s = tanhf(s);
        else if (act == 2) s = fmaxf(s, 0.f);
        out[r] = s;
    }
}

// ---------- softmax over 128 values, in place (1 block, 64 threads) ----------
__global__ void softmax128_kernel(float* __restrict__ logits) {
    int t = threadIdx.x;  // 0..63
    float a = logits[t], b = logits[t + 64];
    float m = fmaxf(a, b);
    for (int off = 32; off > 0; off >>= 1) m = fmaxf(m, __shfl_xor(m, off, 64));
    float ea = expf(a - m), eb = expf(b - m);
    float s = ea + eb;
    for (int off = 32; off > 0; off >>= 1) s += __shfl_xor(s, off, 64);
    logits[t] = ea / s;
    logits[t + 64] = eb / s;
}

// ---------- attn_applied[j] = sum_l w[l] * enc[l][j] ----------
__global__ void attn_apply_kernel(const float* __restrict__ wts,
                                  const float* __restrict__ enc,
                                  float* __restrict__ out) {
    int j = blockIdx.x * blockDim.x + threadIdx.x;
    if (j >= HID) return;
    float acc = 0.f;
    for (int l = 0; l < MAXLEN; ++l) acc += wts[l] * enc[(size_t)l * HID + j];
    out[j] = acc;
}

// ---------- single matvec (K=HID): out[r] = W[r]·x + b[r] ----------
__global__ void matvec_kernel(const float* __restrict__ W, const float* __restrict__ x,
                              const float* __restrict__ bias, float* __restrict__ out) {
    int r = blockIdx.x;
    const float4* w = (const float4*)(W + (size_t)r * HID);
    const float4* v = (const float4*)x;
    const int K4 = HID / 4;
    float p = 0.f;
    for (int i = threadIdx.x; i < K4; i += blockDim.x) {
        float4 a = w[i], b = v[i];
        p += a.x * b.x + a.y * b.y + a.z * b.z + a.w * b.w;
    }
    float s = block_reduce_sum256(p);
    if (threadIdx.x == 0) out[r] = s + bias[r];
}

// ---------- log_softmax over n values, in place (1 block, 1024 threads) ----------
__global__ void log_softmax_kernel(float* __restrict__ io, int n) {
    __shared__ float red[16];
    const int t = threadIdx.x;        // 0..1023 (16 waves)
    const int lane = t & 63, w = t >> 6;
    // phase 1: max
    float m = -INFINITY;
    for (int i = t; i < n; i += 1024) m = fmaxf(m, io[i]);
    for (int off = 32; off > 0; off >>= 1) m = fmaxf(m, __shfl_xor(m, off, 64));
    if (lane == 0) red[w] = m;
    __syncthreads();
    float bm = red[0];
    for (int i = 1; i < 16; ++i) bm = fmaxf(bm, red[i]);
    __syncthreads();
    // phase 2: sum of exp
    float s = 0.f;
    for (int i = t; i < n; i += 1024) s += expf(io[i] - bm);
    for (int off = 32; off > 0; off >>= 1) s += __shfl_xor(s, off, 64);
    if (lane == 0) red[w] = s;
    __syncthreads();
    float bs = 0.f;
    for (int i = 0; i < 16; ++i) bs += red[i];
    float lg = bm + logf(bs);
    __syncthreads();
    // phase 3: write
    for (int i = t; i < n; i += 1024) io[i] -= lg;
}

extern "C" void kernel_launch(void* const* d_in, const int* in_sizes, int n_in,
                              void* d_out, int out_size, void* d_ws, size_t ws_size,
                              hipStream_t stream) {
    const int*   tok    = (const int*)  d_in[0];
    const float* hidden = (const float*)d_in[1];
    const float* enc    = (const float*)d_in[2];
    const float* emb    = (const float*)d_in[3];
    const float* attn_W = (const float*)d_in[4];
    const float* attn_b = (const float*)d_in[5];
    const float* comb_W = (const float*)d_in[6];
    const float* comb_b = (const float*)d_in[7];
    const float* W_ih   = (const float*)d_in[8];
    const float* W_hh   = (const float*)d_in[9];
    const float* b_ih   = (const float*)d_in[10];
    const float* b_hh   = (const float*)d_in[11];
    const float* out_W  = (const float*)d_in[12];
    const float* out_b  = (const float*)d_in[13];
    float* out = (float*)d_out;

    float* ws = (float*)d_ws;
    float* X  = ws;              // [2048] embedding row
    float* H1 = ws + 2048;       // [2048] hidden after rnn step 1
    float* AL = ws + 4096;       // [128]  attn logits -> weights
    float* AA = ws + 6144;       // [2048] attn applied
    float* O  = ws + 8192;       // [2048] combined+relu
    float* OH = ws + 10240;      // [2048] hidden after rnn step 2

    // 0. x = emb[tok]
    gather_row_kernel<<<HID / 256, 256, 0, stream>>>(emb, tok, X);
    // 1. H1 = tanh(W_ih·x + W_hh·h + b_ih + b_hh)
    dual_matvec_kernel<<<HID, 256, 0, stream>>>(W_ih, X, W_hh, hidden, b_ih, b_hh, H1, 1);
    // 2. AL = attn_W·[x; H1] + attn_b
    concat_matvec_kernel<<<MAXLEN, 256, 0, stream>>>(attn_W, X, H1, attn_b, AL, 0);
    // 3. softmax(AL)
    softmax128_kernel<<<1, 64, 0, stream>>>(AL);
    // 4. AA = AL·enc
    attn_apply_kernel<<<HID / 256, 256, 0, stream>>>(AL, enc, AA);
    // 5. O = relu(comb_W·[x; AA] + comb_b)
    concat_matvec_kernel<<<HID, 256, 0, stream>>>(comb_W, X, AA, comb_b, O, 2);
    // 6. OH = tanh(W_ih·O + W_hh·H1 + b_ih + b_hh)
    dual_matvec_kernel<<<HID, 256, 0, stream>>>(W_ih, O, W_hh, H1, b_ih, b_hh, OH, 1);
    // 7. out = out_W·OH + out_b   (the big one: 32000 x 2048)
    matvec_kernel<<<VOCAB, 256, 0, stream>>>(out_W, OH, out_b, out);
    // 8. log_softmax in place
    log_softmax_kernel<<<1, 1024, 0, stream>>>(out, VOCAB);
}